// Round 3
// baseline (1068.258 us; speedup 1.0000x reference)
//
#include <hip/hip_runtime.h>
#include <math.h>

#define HW    1024   // 32*32 pixels
#define CIN   1024
#define CCTX  28
#define CALL  1052
#define COUT  2048
#define CCHNK 512    // conv output channels per chunk
#define NCHNK 4

// ---------------------------------------------------------------------------
// Kernel 1: per-pixel feature L2 norm (clamped, F.normalize style)
// ---------------------------------------------------------------------------
__global__ void pnorm_kernel(const float* __restrict__ src, const float* __restrict__ tgt,
                             float* __restrict__ pnorm) {
    int img = blockIdx.x;
    int p = blockIdx.y * 64 + threadIdx.x;
    const float* feat = (img < 4) ? src + (size_t)img * CIN * HW
                                  : tgt + (size_t)(img - 4) * CIN * HW;
    float ss = 0.f;
    for (int c = 0; c < CIN; ++c) {
        float v = feat[(size_t)c * HW + p];
        ss = fmaf(v, v, ss);
    }
    pnorm[img * HW + p] = fmaxf(sqrtf(ss), 1e-12f);
}

// ---------------------------------------------------------------------------
// Kernel 2: shifted local correlations on L2-normalized features.
// ctx[img][o][p] = <feat(.,p2)/|.|, feat(.,p)/|.|>, 0 if shifted pos OOB
// ---------------------------------------------------------------------------
__global__ void ctx_kernel(const float* __restrict__ src, const float* __restrict__ tgt,
                           const float* __restrict__ pnorm, float* __restrict__ ctx) {
    int img = blockIdx.x;
    int y = blockIdx.y;
    int tid = threadIdx.x;
    int o = tid >> 5;   // 0..27
    int x = tid & 31;
    const float* feat = (img < 4) ? src + (size_t)img * CIN * HW
                                  : tgt + (size_t)(img - 4) * CIN * HW;
    int g = o / 7, i = o % 7;
    int r, c;
    if (g == 0)      { r = i; c = i; }
    else if (g == 1) { r = i; c = 3; }
    else if (g == 2) { r = i; c = 6 - i; }
    else             { r = 3; c = i; }
    int y2 = y + r - 3, x2 = x + c - 3;
    int p = y * 32 + x;
    float outv = 0.f;
    if (y2 >= 0 && y2 < 32 && x2 >= 0 && x2 < 32) {
        int p2 = y2 * 32 + x2;
        const float* f0 = feat + p;
        const float* f1 = feat + p2;
        float acc = 0.f;
        for (int ch = 0; ch < CIN; ++ch)
            acc = fmaf(f0[(size_t)ch * HW], f1[(size_t)ch * HW], acc);
        outv = acc / (pnorm[img * HW + p] * pnorm[img * HW + p2]);
    }
    ctx[((size_t)img * CCTX + o) * HW + p] = outv;
}

// ---------------------------------------------------------------------------
// Kernel 3: 1x1 conv GEMM for one chunk of 512 output channels.
// chunkbuf[img][o-c0][p] = relu(W[o]·X[:,p] + b[o]),  X = [feat; ctx] (1052)
// Also accumulates per-pixel sum-of-squares into nrm_parts[img][mb][p]
// (non-atomic += ; chunk launches are stream-ordered -> deterministic).
// ---------------------------------------------------------------------------
__global__ __launch_bounds__(256) void conv_chunk(const float* __restrict__ src,
                                                  const float* __restrict__ tgt,
                                                  const float* __restrict__ ctx,
                                                  const float* __restrict__ w,
                                                  const float* __restrict__ bias,
                                                  float* __restrict__ chunkbuf,
                                                  float* __restrict__ nrm_parts,
                                                  int c0) {
    __shared__ float As[16][64];
    __shared__ float Xs[16][64];
    __shared__ float Ns[16][64];
    int img = blockIdx.z;
    int mb = blockIdx.y;            // 0..7 within chunk
    int m0g = c0 + mb * 64;         // global output-channel base
    int n0 = blockIdx.x * 64;
    const float* feat = (img < 4) ? src + (size_t)img * CIN * HW
                                  : tgt + (size_t)(img - 4) * CIN * HW;
    const float* ctxi = ctx + (size_t)img * CCTX * HW;
    int tid = threadIdx.x;
    int tx = tid & 15, ty = tid >> 4;
    int am = tid >> 2, ak = (tid & 3) * 4;
    int xk = tid >> 4, xn = (tid & 15) * 4;
    float acc[4][4] = {};
    for (int k0 = 0; k0 < CALL; k0 += 16) {
#pragma unroll
        for (int j = 0; j < 4; ++j) {
            int kk = k0 + ak + j;
            As[ak + j][am] = (kk < CALL) ? w[(size_t)(m0g + am) * CALL + kk] : 0.f;
        }
        {
            int crow = k0 + xk;
            float4 v = make_float4(0.f, 0.f, 0.f, 0.f);
            if (crow < CIN)       v = *(const float4*)(feat + (size_t)crow * HW + n0 + xn);
            else if (crow < CALL) v = *(const float4*)(ctxi + (size_t)(crow - CIN) * HW + n0 + xn);
            *(float4*)&Xs[xk][xn] = v;
        }
        __syncthreads();
#pragma unroll
        for (int k = 0; k < 16; ++k) {
            float4 a = *(const float4*)&As[k][ty * 4];
            float4 b = *(const float4*)&Xs[k][tx * 4];
            float av[4] = {a.x, a.y, a.z, a.w};
            float bv[4] = {b.x, b.y, b.z, b.w};
#pragma unroll
            for (int i2 = 0; i2 < 4; ++i2)
#pragma unroll
                for (int j2 = 0; j2 < 4; ++j2)
                    acc[i2][j2] = fmaf(av[i2], bv[j2], acc[i2][j2]);
        }
        __syncthreads();
    }
    float psum[4] = {0.f, 0.f, 0.f, 0.f};
#pragma unroll
    for (int i2 = 0; i2 < 4; ++i2) {
        int oloc = mb * 64 + ty * 4 + i2;       // channel within chunk
        float bv = bias[c0 + oloc];
#pragma unroll
        for (int j2 = 0; j2 < 4; ++j2) {
            float v = fmaxf(acc[i2][j2] + bv, 0.f);
            chunkbuf[((size_t)img * CCHNK + oloc) * HW + n0 + tx * 4 + j2] = v;
            psum[j2] = fmaf(v, v, psum[j2]);
        }
    }
#pragma unroll
    for (int j2 = 0; j2 < 4; ++j2) Ns[ty][tx * 4 + j2] = psum[j2];
    __syncthreads();
    if (tid < 64) {
        float s = 0.f;
#pragma unroll
        for (int r = 0; r < 16; ++r) s += Ns[r][tid];
        nrm_parts[((size_t)img * 8 + mb) * HW + n0 + tid] += s;   // pre-zeroed; sequential chunks
    }
}

// ---------------------------------------------------------------------------
// Kernel 4: correlation GEMM chunk accumulate:
// corrT[b][t][s] += sum_{k<512} tgtchunk[k][t] * srcchunk[k][s]
// ---------------------------------------------------------------------------
__global__ __launch_bounds__(256) void corr_chunk(const float* __restrict__ chunkbuf,
                                                  float* __restrict__ corrT) {
    __shared__ float As[16][64];   // tgt tile [k][t]
    __shared__ float Bs[16][64];   // src tile [k][s]
    int b = blockIdx.z;
    int t0 = blockIdx.y * 64;
    int s0 = blockIdx.x * 64;
    const float* tg = chunkbuf + (size_t)(4 + b) * CCHNK * HW;
    const float* sr = chunkbuf + (size_t)b * CCHNK * HW;
    int tid = threadIdx.x;
    int tx = tid & 15, ty = tid >> 4;
    int xk = tid >> 4, xn = (tid & 15) * 4;
    float acc[4][4] = {};
    for (int k0 = 0; k0 < CCHNK; k0 += 16) {
        *(float4*)&As[xk][xn] = *(const float4*)(tg + (size_t)(k0 + xk) * HW + t0 + xn);
        *(float4*)&Bs[xk][xn] = *(const float4*)(sr + (size_t)(k0 + xk) * HW + s0 + xn);
        __syncthreads();
#pragma unroll
        for (int k = 0; k < 16; ++k) {
            float4 a = *(const float4*)&As[k][ty * 4];
            float4 bb = *(const float4*)&Bs[k][tx * 4];
            float av[4] = {a.x, a.y, a.z, a.w};
            float bv[4] = {bb.x, bb.y, bb.z, bb.w};
#pragma unroll
            for (int i2 = 0; i2 < 4; ++i2)
#pragma unroll
                for (int j2 = 0; j2 < 4; ++j2)
                    acc[i2][j2] = fmaf(av[i2], bv[j2], acc[i2][j2]);
        }
        __syncthreads();
    }
#pragma unroll
    for (int i2 = 0; i2 < 4; ++i2) {
        int t = t0 + ty * 4 + i2;
        float4* p = (float4*)(corrT + ((size_t)b * HW + t) * HW + s0 + tx * 4);
        float4 old = *p;
        old.x += acc[i2][0]; old.y += acc[i2][1];
        old.z += acc[i2][2]; old.w += acc[i2][3];
        *p = old;
    }
}

// ---------------------------------------------------------------------------
// Kernel 5: nrm_sq[img][p] = sum_mb nrm_parts[img][mb][p]
// ---------------------------------------------------------------------------
__global__ void nrm_reduce(const float* __restrict__ nrm_parts, float* __restrict__ nrm_sq) {
    int img = blockIdx.y;
    int p = blockIdx.x * 256 + threadIdx.x;
    float s = 0.f;
#pragma unroll
    for (int mb = 0; mb < 8; ++mb)
        s += nrm_parts[((size_t)img * 8 + mb) * HW + p];
    nrm_sq[img * HW + p] = s;
}

// ---------------------------------------------------------------------------
// Kernel 6: normalize corrT in place by sqrt(nrm+1e-6) products, emit
// tmax[b][t] (exact, block owns full rows) and smax partial col-maxes.
// grid (16 tgroups, 4 b), 256 threads; each thread owns 4 s-columns.
// ---------------------------------------------------------------------------
__global__ __launch_bounds__(256) void corr_finish1(float* __restrict__ corrT,
                                                    const float* __restrict__ nrm_sq,
                                                    float* __restrict__ smax_parts,
                                                    float* __restrict__ tmax) {
    __shared__ float wmax[64][4];
    int tg = blockIdx.x, b = blockIdx.y;
    int tid = threadIdx.x;
    int lane = tid & 63, wv = tid >> 6;
    int s4 = tid * 4;
    float ns0 = sqrtf(nrm_sq[(size_t)b * HW + s4 + 0] + 1e-6f);
    float ns1 = sqrtf(nrm_sq[(size_t)b * HW + s4 + 1] + 1e-6f);
    float ns2 = sqrtf(nrm_sq[(size_t)b * HW + s4 + 2] + 1e-6f);
    float ns3 = sqrtf(nrm_sq[(size_t)b * HW + s4 + 3] + 1e-6f);
    float cm0 = 0.f, cm1 = 0.f, cm2 = 0.f, cm3 = 0.f;
    for (int r = 0; r < 64; ++r) {
        int t = tg * 64 + r;
        float nt = sqrtf(nrm_sq[(size_t)(4 + b) * HW + t] + 1e-6f);
        float4* p = (float4*)(corrT + ((size_t)b * HW + t) * HW + s4);
        float4 v = *p;
        v.x /= (nt * ns0); v.y /= (nt * ns1);
        v.z /= (nt * ns2); v.w /= (nt * ns3);
        *p = v;
        cm0 = fmaxf(cm0, v.x); cm1 = fmaxf(cm1, v.y);
        cm2 = fmaxf(cm2, v.z); cm3 = fmaxf(cm3, v.w);
        float pm = fmaxf(fmaxf(v.x, v.y), fmaxf(v.z, v.w));
#pragma unroll
        for (int off = 32; off >= 1; off >>= 1) pm = fmaxf(pm, __shfl_down(pm, off));
        if (lane == 0) wmax[r][wv] = pm;
    }
    __syncthreads();
    if (tid < 64) {
        float m = fmaxf(fmaxf(wmax[tid][0], wmax[tid][1]), fmaxf(wmax[tid][2], wmax[tid][3]));
        tmax[(size_t)b * HW + tg * 64 + tid] = m;
    }
    float* sp = smax_parts + ((size_t)(b * 16 + tg)) * HW + s4;
    sp[0] = cm0; sp[1] = cm1; sp[2] = cm2; sp[3] = cm3;
}

// ---------------------------------------------------------------------------
// Kernel 7: smax[b][s] = max over 16 tgroup partials
// ---------------------------------------------------------------------------
__global__ void corr_finish2(const float* __restrict__ smax_parts, float* __restrict__ smax) {
    int b = blockIdx.y;
    int s = blockIdx.x * 256 + threadIdx.x;
    float m = 0.f;
#pragma unroll
    for (int tg = 0; tg < 16; ++tg)
        m = fmaxf(m, smax_parts[((size_t)(b * 16 + tg)) * HW + s]);
    smax[(size_t)b * HW + s] = m;
}

// ---------------------------------------------------------------------------
// Kernel 8: final — per (b, t') 4-tap bilinear over t of FILTERED corr rows,
// upsample over source grid, sharp softmax + soft-argmax -> flow.
// Filter f(x) = x^3 / (smax[s]*tmax[t]) applied per tap row BEFORE combine
// (filter precedes resize in the reference).
// ---------------------------------------------------------------------------
__global__ __launch_bounds__(256) void final_kernel(const float* __restrict__ corrT,
                                                    const float* __restrict__ smax,
                                                    const float* __restrict__ tmax,
                                                    float* __restrict__ out) {
    __shared__ float vsh[1024];
    __shared__ float rbuf[16];
    int b = blockIdx.z;
    int typ = blockIdx.y;
    int txp = blockIdx.x;
    int tid = threadIdx.x;

    float fy = typ * (31.0f / 63.0f);
    int y0 = min((int)fy, 31); int y1 = min(y0 + 1, 31);
    float wy = fy - (float)y0;
    float fx = txp * (31.0f / 63.0f);
    int x0 = min((int)fx, 31); int x1 = min(x0 + 1, 31);
    float wx = fx - (float)x0;
    int tA = y0 * 32 + x0, tB = y0 * 32 + x1, tC = y1 * 32 + x0, tD = y1 * 32 + x1;
    const float* base = corrT + (size_t)b * HW * HW;
    const float* rA = base + (size_t)tA * HW;
    const float* rB = base + (size_t)tB * HW;
    const float* rC = base + (size_t)tC * HW;
    const float* rD = base + (size_t)tD * HW;
    float tmA_ = tmax[b * HW + tA]; if (tmA_ == 0.f) tmA_ = 1e-30f;
    float tmB_ = tmax[b * HW + tB]; if (tmB_ == 0.f) tmB_ = 1e-30f;
    float tmC_ = tmax[b * HW + tC]; if (tmC_ == 0.f) tmC_ = 1e-30f;
    float tmD_ = tmax[b * HW + tD]; if (tmD_ == 0.f) tmD_ = 1e-30f;
    float itA = 1.f / tmA_, itB = 1.f / tmB_, itC = 1.f / tmC_, itD = 1.f / tmD_;
    float wA = (1.f - wy) * (1.f - wx), wB = (1.f - wy) * wx;
    float wC = wy * (1.f - wx), wD = wy * wx;
#pragma unroll
    for (int u = 0; u < 4; ++u) {
        int s = u * 256 + tid;
        float sm = smax[b * HW + s]; if (sm == 0.f) sm = 1e-30f;
        float is = 1.f / sm;
        float a = rA[s]; a = a * a * a * is * itA;
        float b2 = rB[s]; b2 = b2 * b2 * b2 * is * itB;
        float c2 = rC[s]; c2 = c2 * c2 * c2 * is * itC;
        float d2 = rD[s]; d2 = d2 * d2 * d2 * is * itD;
        vsh[s] = wA * a + wB * b2 + wC * c2 + wD * d2;
    }
    __syncthreads();

    float cv[16];
    float lmax = -1e30f;
#pragma unroll
    for (int u = 0; u < 16; ++u) {
        int sp = u * 256 + tid;
        int i = sp >> 6, j = sp & 63;
        float gy = i * (31.0f / 63.0f);
        int sy0 = min((int)gy, 31); int sy1 = min(sy0 + 1, 31);
        float wyy = gy - (float)sy0;
        float gx = j * (31.0f / 63.0f);
        int sx0 = min((int)gx, 31); int sx1 = min(sx0 + 1, 31);
        float wxx = gx - (float)sx0;
        float v00 = vsh[sy0 * 32 + sx0], v01 = vsh[sy0 * 32 + sx1];
        float v10 = vsh[sy1 * 32 + sx0], v11 = vsh[sy1 * 32 + sx1];
        float c = (v00 * (1.f - wxx) + v01 * wxx) * (1.f - wyy)
                + (v10 * (1.f - wxx) + v11 * wxx) * wyy;
        cv[u] = c * 50.0f;   // /BETA
        lmax = fmaxf(lmax, cv[u]);
    }
#pragma unroll
    for (int off = 32; off >= 1; off >>= 1) lmax = fmaxf(lmax, __shfl_down(lmax, off));
    int lane = tid & 63, wv = tid >> 6;
    if (lane == 0) rbuf[wv] = lmax;
    __syncthreads();
    if (tid == 0) {
        float m = rbuf[0];
        for (int i = 1; i < 4; ++i) m = fmaxf(m, rbuf[i]);
        rbuf[0] = m;
    }
    __syncthreads();
    float m = rbuf[0];

    float e0 = 0.f, ex = 0.f, ey = 0.f;
#pragma unroll
    for (int u = 0; u < 16; ++u) {
        int sp = u * 256 + tid;
        int i = sp >> 6, j = sp & 63;
        float e = __expf(cv[u] - m);
        e0 += e;
        ex = fmaf(e, j * (2.0f / 63.0f) - 1.0f, ex);
        ey = fmaf(e, i * (2.0f / 63.0f) - 1.0f, ey);
    }
#pragma unroll
    for (int off = 32; off >= 1; off >>= 1) {
        e0 += __shfl_down(e0, off);
        ex += __shfl_down(ex, off);
        ey += __shfl_down(ey, off);
    }
    if (lane == 0) { rbuf[4 + wv] = e0; rbuf[8 + wv] = ex; rbuf[12 + wv] = ey; }
    __syncthreads();
    if (tid == 0) {
        float s0 = rbuf[4] + rbuf[5] + rbuf[6] + rbuf[7];
        float sx = rbuf[8] + rbuf[9] + rbuf[10] + rbuf[11];
        float sy = rbuf[12] + rbuf[13] + rbuf[14] + rbuf[15];
        float gx = sx / s0, gy = sy / s0;
        float mx = (gx + 1.f) * 31.5f;
        float my = (gy + 1.f) * 31.5f;
        out[(((size_t)b * 2 + 0) * 64 + typ) * 64 + txp] = mx - (float)txp;
        out[(((size_t)b * 2 + 1) * 64 + typ) * 64 + txp] = my - (float)typ;
    }
}

// ---------------------------------------------------------------------------
// Workspace layout (floats):                         total ~33.5 MiB
//   corrT        4*1024*1024 = 4194304     (zeroed each call)
//   nrm_parts    8*8*1024    = 65536       (zeroed each call)
//   nrm_sq       8192
//   smax         4096
//   smax_parts   4*16*1024   = 65536
//   tmax         4096
//   pnorm        8192
//   ctxbuf       8*28*1024   = 229376
//   chunkbuf     8*512*1024  = 4194304
// ---------------------------------------------------------------------------
extern "C" void kernel_launch(void* const* d_in, const int* in_sizes, int n_in,
                              void* d_out, int out_size, void* d_ws, size_t ws_size,
                              hipStream_t stream) {
    const float* src  = (const float*)d_in[0];
    const float* tgt  = (const float*)d_in[1];
    const float* sw   = (const float*)d_in[2];
    const float* sb   = (const float*)d_in[3];
    float* out = (float*)d_out;

    float* corrT      = (float*)d_ws;
    float* nrm_parts  = corrT + 4194304;
    float* nrm_sq     = nrm_parts + 65536;
    float* smax       = nrm_sq + 8192;
    float* smax_parts = smax + 4096;
    float* tmax       = smax_parts + 65536;
    float* pnorm      = tmax + 4096;
    float* ctxbuf     = pnorm + 8192;
    float* chunkbuf   = ctxbuf + 229376;

    // zero corrT + nrm_parts (contiguous): (4194304 + 65536) floats
    hipMemsetAsync(corrT, 0, (size_t)(4194304 + 65536) * sizeof(float), stream);

    pnorm_kernel<<<dim3(8, 16), 64, 0, stream>>>(src, tgt, pnorm);
    ctx_kernel<<<dim3(8, 32), 896, 0, stream>>>(src, tgt, pnorm, ctxbuf);

    for (int c = 0; c < NCHNK; ++c) {
        conv_chunk<<<dim3(16, 8, 8), 256, 0, stream>>>(src, tgt, ctxbuf, sw, sb,
                                                       chunkbuf, nrm_parts, c * CCHNK);
        corr_chunk<<<dim3(16, 16, 4), 256, 0, stream>>>(chunkbuf, corrT);
    }

    nrm_reduce<<<dim3(4, 8), 256, 0, stream>>>(nrm_parts, nrm_sq);
    corr_finish1<<<dim3(16, 4), 256, 0, stream>>>(corrT, nrm_sq, smax_parts, tmax);
    corr_finish2<<<dim3(4, 4), 256, 0, stream>>>(smax_parts, smax);
    final_kernel<<<dim3(64, 64, 4), 256, 0, stream>>>(corrT, smax, tmax, out);
}

// Round 4
// 983.248 us; speedup vs baseline: 1.0865x; 1.0865x over previous
//
#include <hip/hip_runtime.h>
#include <math.h>

#define HW    1024   // 32*32 pixels
#define CIN   1024
#define CCTX  28
#define CALL  1052
#define COUT  2048
#define CCHNK 512
#define NCHNK 4

// ---------------------------------------------------------------------------
// Kernel 1: per-pixel feature L2 norm (clamped, F.normalize style)
// ---------------------------------------------------------------------------
__global__ void pnorm_kernel(const float* __restrict__ src, const float* __restrict__ tgt,
                             float* __restrict__ pnorm) {
    int img = blockIdx.x;
    int p = blockIdx.y * 64 + threadIdx.x;
    const float* feat = (img < 4) ? src + (size_t)img * CIN * HW
                                  : tgt + (size_t)(img - 4) * CIN * HW;
    float ss = 0.f;
    for (int c = 0; c < CIN; ++c) {
        float v = feat[(size_t)c * HW + p];
        ss = fmaf(v, v, ss);
    }
    pnorm[img * HW + p] = fmaxf(sqrtf(ss), 1e-12f);
}

// ---------------------------------------------------------------------------
// Kernel 2: shifted local correlations on L2-normalized features.
// ---------------------------------------------------------------------------
__global__ void ctx_kernel(const float* __restrict__ src, const float* __restrict__ tgt,
                           const float* __restrict__ pnorm, float* __restrict__ ctx) {
    int img = blockIdx.x;
    int y = blockIdx.y;
    int tid = threadIdx.x;
    int o = tid >> 5;   // 0..27
    int x = tid & 31;
    const float* feat = (img < 4) ? src + (size_t)img * CIN * HW
                                  : tgt + (size_t)(img - 4) * CIN * HW;
    int g = o / 7, i = o % 7;
    int r, c;
    if (g == 0)      { r = i; c = i; }
    else if (g == 1) { r = i; c = 3; }
    else if (g == 2) { r = i; c = 6 - i; }
    else             { r = 3; c = i; }
    int y2 = y + r - 3, x2 = x + c - 3;
    int p = y * 32 + x;
    float outv = 0.f;
    if (y2 >= 0 && y2 < 32 && x2 >= 0 && x2 < 32) {
        int p2 = y2 * 32 + x2;
        const float* f0 = feat + p;
        const float* f1 = feat + p2;
        float acc = 0.f;
        for (int ch = 0; ch < CIN; ++ch)
            acc = fmaf(f0[(size_t)ch * HW], f1[(size_t)ch * HW], acc);
        outv = acc / (pnorm[img * HW + p] * pnorm[img * HW + p2]);
    }
    ctx[((size_t)img * CCTX + o) * HW + p] = outv;
}

// ---------------------------------------------------------------------------
// Kernel 3: conv chunk GEMM, 64x128 tile, 4x8/thread, double-buffered LDS.
// chunkbuf[img][o-c0][p] = relu(W[o]·X[:,p]+b[o]); nrm partial per m-block.
// grid (8 nblk, 8 mblk, 8 img), 256 threads.
// ---------------------------------------------------------------------------
template <bool FIRST>
__global__ __launch_bounds__(256) void conv_chunk(const float* __restrict__ src,
                                                  const float* __restrict__ tgt,
                                                  const float* __restrict__ ctxb,
                                                  const float* __restrict__ w,
                                                  const float* __restrict__ bias,
                                                  float* __restrict__ chunkbuf,
                                                  float* __restrict__ nrm_parts,
                                                  int c0) {
    __shared__ float As[2][16][68];   // [k][m], padded (+4) for transpose-store
    __shared__ float Bs[2][16][128];  // [k][n]
    int img = blockIdx.z;
    int mb = blockIdx.y;                    // m-block within chunk (0..7)
    int m0g = c0 + mb * 64;
    int n0 = blockIdx.x * 128;
    const float* feat = (img < 4) ? src + (size_t)img * CIN * HW
                                  : tgt + (size_t)(img - 4) * CIN * HW;
    const float* ctxi = ctxb + (size_t)img * CCTX * HW;
    int tid = threadIdx.x;
    int tm = tid >> 4, tn = tid & 15;
    int arow = tid >> 2, akq = tid & 3;     // A stage: 64 rows x 4 k-quads
    int brow = tid >> 4, bc = (tid & 15) * 4;

    float4 ar, br0, br1;
    auto loadA = [&](int k0) {
        if (k0 + akq * 4 + 4 <= CALL)
            ar = *(const float4*)(w + (size_t)(m0g + arow) * CALL + k0 + akq * 4);
        else
            ar = make_float4(0.f, 0.f, 0.f, 0.f);
    };
    auto loadB = [&](int k0) {
        int crow = k0 + brow;
        if (crow < CIN) {
            const float* rp = feat + (size_t)crow * HW + n0;
            br0 = *(const float4*)(rp + bc);
            br1 = *(const float4*)(rp + bc + 64);
        } else if (crow < CALL) {
            const float* rp = ctxi + (size_t)(crow - CIN) * HW + n0;
            br0 = *(const float4*)(rp + bc);
            br1 = *(const float4*)(rp + bc + 64);
        } else {
            br0 = make_float4(0.f, 0.f, 0.f, 0.f); br1 = br0;
        }
    };
    auto storeLDS = [&](int buf) {
        As[buf][akq * 4 + 0][arow] = ar.x;
        As[buf][akq * 4 + 1][arow] = ar.y;
        As[buf][akq * 4 + 2][arow] = ar.z;
        As[buf][akq * 4 + 3][arow] = ar.w;
        *(float4*)&Bs[buf][brow][bc] = br0;
        *(float4*)&Bs[buf][brow][bc + 64] = br1;
    };

    loadA(0); loadB(0); storeLDS(0);
    __syncthreads();

    float acc[4][8] = {};
    const int NT = 66;                       // ceil(1052/16)
    for (int t = 0; t < NT; ++t) {
        int cur = t & 1;
        if (t + 1 < NT) { loadA((t + 1) * 16); loadB((t + 1) * 16); }
#pragma unroll
        for (int k = 0; k < 16; ++k) {
            float4 a  = *(const float4*)&As[cur][k][tm * 4];
            float4 p0 = *(const float4*)&Bs[cur][k][tn * 4];
            float4 p1 = *(const float4*)&Bs[cur][k][tn * 4 + 64];
            float av[4] = {a.x, a.y, a.z, a.w};
            float bv[8] = {p0.x, p0.y, p0.z, p0.w, p1.x, p1.y, p1.z, p1.w};
#pragma unroll
            for (int i = 0; i < 4; ++i)
#pragma unroll
                for (int j = 0; j < 8; ++j)
                    acc[i][j] = fmaf(av[i], bv[j], acc[i][j]);
        }
        if (t + 1 < NT) storeLDS(cur ^ 1);
        __syncthreads();
    }

    // epilogue: bias + relu, store, per-pixel sum-of-squares partials
    float psum[8] = {};
#pragma unroll
    for (int i = 0; i < 4; ++i) {
        int oloc = mb * 64 + tm * 4 + i;
        float bv = bias[c0 + oloc];
        float4 o0, o1;
        o0.x = fmaxf(acc[i][0] + bv, 0.f); o0.y = fmaxf(acc[i][1] + bv, 0.f);
        o0.z = fmaxf(acc[i][2] + bv, 0.f); o0.w = fmaxf(acc[i][3] + bv, 0.f);
        o1.x = fmaxf(acc[i][4] + bv, 0.f); o1.y = fmaxf(acc[i][5] + bv, 0.f);
        o1.z = fmaxf(acc[i][6] + bv, 0.f); o1.w = fmaxf(acc[i][7] + bv, 0.f);
        float* op = chunkbuf + ((size_t)img * CCHNK + oloc) * HW + n0;
        *(float4*)(op + tn * 4) = o0;
        *(float4*)(op + tn * 4 + 64) = o1;
        psum[0] = fmaf(o0.x, o0.x, psum[0]); psum[1] = fmaf(o0.y, o0.y, psum[1]);
        psum[2] = fmaf(o0.z, o0.z, psum[2]); psum[3] = fmaf(o0.w, o0.w, psum[3]);
        psum[4] = fmaf(o1.x, o1.x, psum[4]); psum[5] = fmaf(o1.y, o1.y, psum[5]);
        psum[6] = fmaf(o1.z, o1.z, psum[6]); psum[7] = fmaf(o1.w, o1.w, psum[7]);
    }
    // reduce over tm via LDS (reuse Bs[0], safe: loop ended with barrier)
#pragma unroll
    for (int j = 0; j < 4; ++j) {
        Bs[0][tm][tn * 4 + j] = psum[j];
        Bs[0][tm][tn * 4 + 64 + j] = psum[4 + j];
    }
    __syncthreads();
    if (tid < 128) {
        float s = 0.f;
#pragma unroll
        for (int r = 0; r < 16; ++r) s += Bs[0][r][tid];
        float* np = nrm_parts + ((size_t)img * 8 + mb) * HW + n0 + tid;
        if (FIRST) *np = s; else *np += s;
    }
}

// ---------------------------------------------------------------------------
// Kernel 4: correlation chunk GEMM, 64(t)x128(s) tile, 4x8/thread, dbuf.
// MODE 0: corrT  = acc ; MODE 1: corrT += acc ;
// MODE 2: corrT = (corrT+acc)/(nt*ns), emit smax/tmax partials.
// grid (8 sblk, 16 tblk, 4 b), 256 threads.
// ---------------------------------------------------------------------------
template <int MODE>
__global__ __launch_bounds__(256) void corr_chunk(const float* __restrict__ chunkbuf,
                                                  const float* __restrict__ nrm_sq,
                                                  float* __restrict__ corrT,
                                                  float* __restrict__ spar,
                                                  float* __restrict__ tpar) {
    __shared__ float As[2][16][64];   // tgt [k][t]
    __shared__ float Bs[2][16][128];  // src [k][s]
    int b = blockIdx.z;
    int t0 = blockIdx.y * 64;
    int s0 = blockIdx.x * 128;
    const float* tg = chunkbuf + (size_t)(4 + b) * CCHNK * HW;
    const float* sr = chunkbuf + (size_t)b * CCHNK * HW;
    int tid = threadIdx.x;
    int tm = tid >> 4, tn = tid & 15;
    int arow = tid >> 4, ac = (tid & 15) * 4;
    int brow = tid >> 4, bc = (tid & 15) * 4;

    float4 ar, br0, br1;
    auto loadAB = [&](int k0) {
        ar  = *(const float4*)(tg + (size_t)(k0 + arow) * HW + t0 + ac);
        const float* rp = sr + (size_t)(k0 + brow) * HW + s0;
        br0 = *(const float4*)(rp + bc);
        br1 = *(const float4*)(rp + bc + 64);
    };
    auto storeLDS = [&](int buf) {
        *(float4*)&As[buf][arow][ac] = ar;
        *(float4*)&Bs[buf][brow][bc] = br0;
        *(float4*)&Bs[buf][brow][bc + 64] = br1;
    };

    loadAB(0); storeLDS(0);
    __syncthreads();

    float acc[4][8] = {};
    const int NT = CCHNK / 16;   // 32
    for (int t = 0; t < NT; ++t) {
        int cur = t & 1;
        if (t + 1 < NT) loadAB((t + 1) * 16);
#pragma unroll
        for (int k = 0; k < 16; ++k) {
            float4 a  = *(const float4*)&As[cur][k][tm * 4];
            float4 p0 = *(const float4*)&Bs[cur][k][tn * 4];
            float4 p1 = *(const float4*)&Bs[cur][k][tn * 4 + 64];
            float av[4] = {a.x, a.y, a.z, a.w};
            float bv[8] = {p0.x, p0.y, p0.z, p0.w, p1.x, p1.y, p1.z, p1.w};
#pragma unroll
            for (int i = 0; i < 4; ++i)
#pragma unroll
                for (int j = 0; j < 8; ++j)
                    acc[i][j] = fmaf(av[i], bv[j], acc[i][j]);
        }
        if (t + 1 < NT) storeLDS(cur ^ 1);
        __syncthreads();
    }

    if (MODE == 0) {
#pragma unroll
        for (int i = 0; i < 4; ++i) {
            float* cp = corrT + ((size_t)b * HW + t0 + tm * 4 + i) * HW + s0;
            *(float4*)(cp + tn * 4) = make_float4(acc[i][0], acc[i][1], acc[i][2], acc[i][3]);
            *(float4*)(cp + tn * 4 + 64) = make_float4(acc[i][4], acc[i][5], acc[i][6], acc[i][7]);
        }
        return;
    }
    // accumulate with previous chunks
#pragma unroll
    for (int i = 0; i < 4; ++i) {
        float* cp = corrT + ((size_t)b * HW + t0 + tm * 4 + i) * HW + s0;
        float4 o0 = *(const float4*)(cp + tn * 4);
        float4 o1 = *(const float4*)(cp + tn * 4 + 64);
        acc[i][0] += o0.x; acc[i][1] += o0.y; acc[i][2] += o0.z; acc[i][3] += o0.w;
        acc[i][4] += o1.x; acc[i][5] += o1.y; acc[i][6] += o1.z; acc[i][7] += o1.w;
        if (MODE == 1) {
            *(float4*)(cp + tn * 4) = make_float4(acc[i][0], acc[i][1], acc[i][2], acc[i][3]);
            *(float4*)(cp + tn * 4 + 64) = make_float4(acc[i][4], acc[i][5], acc[i][6], acc[i][7]);
        }
    }
    if (MODE == 1) return;

    // MODE 2: normalize + store + maxes
    float nt_[4], ns_[8];
#pragma unroll
    for (int i = 0; i < 4; ++i)
        nt_[i] = 1.f / sqrtf(nrm_sq[(size_t)(4 + b) * HW + t0 + tm * 4 + i] + 1e-6f);
#pragma unroll
    for (int j = 0; j < 4; ++j) {
        ns_[j]     = 1.f / sqrtf(nrm_sq[(size_t)b * HW + s0 + tn * 4 + j] + 1e-6f);
        ns_[4 + j] = 1.f / sqrtf(nrm_sq[(size_t)b * HW + s0 + tn * 4 + 64 + j] + 1e-6f);
    }
    float rowmax[4] = {0.f, 0.f, 0.f, 0.f};
    float colmax[8] = {};
#pragma unroll
    for (int i = 0; i < 4; ++i) {
        float* cp = corrT + ((size_t)b * HW + t0 + tm * 4 + i) * HW + s0;
        float4 o0, o1;
#pragma unroll
        for (int j = 0; j < 8; ++j) {
            float v = acc[i][j] * nt_[i] * ns_[j];
            acc[i][j] = v;
            rowmax[i] = fmaxf(rowmax[i], v);
            colmax[j] = fmaxf(colmax[j], v);
        }
        o0 = make_float4(acc[i][0], acc[i][1], acc[i][2], acc[i][3]);
        o1 = make_float4(acc[i][4], acc[i][5], acc[i][6], acc[i][7]);
        *(float4*)(cp + tn * 4) = o0;
        *(float4*)(cp + tn * 4 + 64) = o1;
    }
    // tmax partial (max over this s-block): reduce rowmax across tn lanes
#pragma unroll
    for (int off = 1; off <= 8; off <<= 1) {
#pragma unroll
        for (int i = 0; i < 4; ++i)
            rowmax[i] = fmaxf(rowmax[i], __shfl_xor(rowmax[i], off));
    }
    if (tn == 0) {
#pragma unroll
        for (int i = 0; i < 4; ++i)
            tpar[((size_t)b * 8 + blockIdx.x) * HW + t0 + tm * 4 + i] = rowmax[i];
    }
    // smax partial (max over this t-block): reduce colmax across tm via LDS
#pragma unroll
    for (int j = 0; j < 4; ++j) {
        Bs[0][tm][tn * 4 + j] = colmax[j];
        Bs[0][tm][tn * 4 + 64 + j] = colmax[4 + j];
    }
    __syncthreads();
    if (tid < 128) {
        float m = 0.f;
#pragma unroll
        for (int r = 0; r < 16; ++r) m = fmaxf(m, Bs[0][r][tid]);
        spar[((size_t)b * 16 + blockIdx.y) * HW + s0 + tid] = m;
    }
}

// ---------------------------------------------------------------------------
// Kernel 5: nrm_sq[img][p] = sum_mb nrm_parts[img][mb][p]
// ---------------------------------------------------------------------------
__global__ void nrm_reduce(const float* __restrict__ nrm_parts, float* __restrict__ nrm_sq) {
    int img = blockIdx.y;
    int p = blockIdx.x * 256 + threadIdx.x;
    float s = 0.f;
#pragma unroll
    for (int mb = 0; mb < 8; ++mb)
        s += nrm_parts[((size_t)img * 8 + mb) * HW + p];
    nrm_sq[img * HW + p] = s;
}

// ---------------------------------------------------------------------------
// Kernel 6: combine smax/tmax partials
// ---------------------------------------------------------------------------
__global__ void combine_max(const float* __restrict__ spar, const float* __restrict__ tpar,
                            float* __restrict__ smax, float* __restrict__ tmax) {
    int b = blockIdx.y;
    int i = blockIdx.x * 256 + threadIdx.x;
    float m = 0.f;
#pragma unroll
    for (int q = 0; q < 16; ++q) m = fmaxf(m, spar[((size_t)b * 16 + q) * HW + i]);
    smax[b * HW + i] = m;
    float m2 = 0.f;
#pragma unroll
    for (int q = 0; q < 8; ++q) m2 = fmaxf(m2, tpar[((size_t)b * 8 + q) * HW + i]);
    tmax[b * HW + i] = m2;
}

// ---------------------------------------------------------------------------
// Kernel 7: final — filter (x^3/(smax*tmax)) per tap row, separable bilinear,
// sharp softmax + soft-argmax -> flow.
// ---------------------------------------------------------------------------
__global__ __launch_bounds__(256) void final_kernel(const float* __restrict__ corrT,
                                                    const float* __restrict__ smax,
                                                    const float* __restrict__ tmax,
                                                    float* __restrict__ out) {
    __shared__ float vsh[1024];
    __shared__ float rbuf[16];
    int b = blockIdx.z;
    int typ = blockIdx.y;
    int txp = blockIdx.x;
    int tid = threadIdx.x;

    float fy = typ * (31.0f / 63.0f);
    int y0 = min((int)fy, 31); int y1 = min(y0 + 1, 31);
    float wy = fy - (float)y0;
    float fx = txp * (31.0f / 63.0f);
    int x0 = min((int)fx, 31); int x1 = min(x0 + 1, 31);
    float wx = fx - (float)x0;
    int tA = y0 * 32 + x0, tB = y0 * 32 + x1, tC = y1 * 32 + x0, tD = y1 * 32 + x1;
    const float* base = corrT + (size_t)b * HW * HW;
    const float* rA = base + (size_t)tA * HW;
    const float* rB = base + (size_t)tB * HW;
    const float* rC = base + (size_t)tC * HW;
    const float* rD = base + (size_t)tD * HW;
    float tmA_ = tmax[b * HW + tA]; if (tmA_ == 0.f) tmA_ = 1e-30f;
    float tmB_ = tmax[b * HW + tB]; if (tmB_ == 0.f) tmB_ = 1e-30f;
    float tmC_ = tmax[b * HW + tC]; if (tmC_ == 0.f) tmC_ = 1e-30f;
    float tmD_ = tmax[b * HW + tD]; if (tmD_ == 0.f) tmD_ = 1e-30f;
    float itA = 1.f / tmA_, itB = 1.f / tmB_, itC = 1.f / tmC_, itD = 1.f / tmD_;
    float wA = (1.f - wy) * (1.f - wx), wB = (1.f - wy) * wx;
    float wC = wy * (1.f - wx), wD = wy * wx;
#pragma unroll
    for (int u = 0; u < 4; ++u) {
        int s = u * 256 + tid;
        float sm = smax[b * HW + s]; if (sm == 0.f) sm = 1e-30f;
        float is = 1.f / sm;
        float a = rA[s]; a = a * a * a * is * itA;
        float b2 = rB[s]; b2 = b2 * b2 * b2 * is * itB;
        float c2 = rC[s]; c2 = c2 * c2 * c2 * is * itC;
        float d2 = rD[s]; d2 = d2 * d2 * d2 * is * itD;
        vsh[s] = wA * a + wB * b2 + wC * c2 + wD * d2;
    }
    __syncthreads();

    float cv[16];
    float lmax = -1e30f;
#pragma unroll
    for (int u = 0; u < 16; ++u) {
        int sp = u * 256 + tid;
        int i = sp >> 6, j = sp & 63;
        float gy = i * (31.0f / 63.0f);
        int sy0 = min((int)gy, 31); int sy1 = min(sy0 + 1, 31);
        float wyy = gy - (float)sy0;
        float gx = j * (31.0f / 63.0f);
        int sx0 = min((int)gx, 31); int sx1 = min(sx0 + 1, 31);
        float wxx = gx - (float)sx0;
        float v00 = vsh[sy0 * 32 + sx0], v01 = vsh[sy0 * 32 + sx1];
        float v10 = vsh[sy1 * 32 + sx0], v11 = vsh[sy1 * 32 + sx1];
        float c = (v00 * (1.f - wxx) + v01 * wxx) * (1.f - wyy)
                + (v10 * (1.f - wxx) + v11 * wxx) * wyy;
        cv[u] = c * 50.0f;
        lmax = fmaxf(lmax, cv[u]);
    }
#pragma unroll
    for (int off = 32; off >= 1; off >>= 1) lmax = fmaxf(lmax, __shfl_down(lmax, off));
    int lane = tid & 63, wv = tid >> 6;
    if (lane == 0) rbuf[wv] = lmax;
    __syncthreads();
    if (tid == 0) {
        float m = rbuf[0];
        for (int i = 1; i < 4; ++i) m = fmaxf(m, rbuf[i]);
        rbuf[0] = m;
    }
    __syncthreads();
    float m = rbuf[0];

    float e0 = 0.f, ex = 0.f, ey = 0.f;
#pragma unroll
    for (int u = 0; u < 16; ++u) {
        int sp = u * 256 + tid;
        int i = sp >> 6, j = sp & 63;
        float e = __expf(cv[u] - m);
        e0 += e;
        ex = fmaf(e, j * (2.0f / 63.0f) - 1.0f, ex);
        ey = fmaf(e, i * (2.0f / 63.0f) - 1.0f, ey);
    }
#pragma unroll
    for (int off = 32; off >= 1; off >>= 1) {
        e0 += __shfl_down(e0, off);
        ex += __shfl_down(ex, off);
        ey += __shfl_down(ey, off);
    }
    if (lane == 0) { rbuf[4 + wv] = e0; rbuf[8 + wv] = ex; rbuf[12 + wv] = ey; }
    __syncthreads();
    if (tid == 0) {
        float s0 = rbuf[4] + rbuf[5] + rbuf[6] + rbuf[7];
        float sx = rbuf[8] + rbuf[9] + rbuf[10] + rbuf[11];
        float sy = rbuf[12] + rbuf[13] + rbuf[14] + rbuf[15];
        float gx = sx / s0, gy = sy / s0;
        float mx = (gx + 1.f) * 31.5f;
        float my = (gy + 1.f) * 31.5f;
        out[(((size_t)b * 2 + 0) * 64 + typ) * 64 + txp] = mx - (float)txp;
        out[(((size_t)b * 2 + 1) * 64 + typ) * 64 + txp] = my - (float)typ;
    }
}

// ---------------------------------------------------------------------------
// Workspace (floats), total 8,773,632 = 33.47 MiB (identical to proven layout):
//   corrT 4194304 | nrm_parts 65536 (tpar aliases it after nrm_reduce)
//   nrm_sq 8192 | smax 4096 | spar 65536 | tmax 4096 | pnorm 8192
//   ctxbuf 229376 | chunkbuf 4194304
// No memset: every buffer is written before it is read.
// ---------------------------------------------------------------------------
extern "C" void kernel_launch(void* const* d_in, const int* in_sizes, int n_in,
                              void* d_out, int out_size, void* d_ws, size_t ws_size,
                              hipStream_t stream) {
    const float* src  = (const float*)d_in[0];
    const float* tgt  = (const float*)d_in[1];
    const float* sw   = (const float*)d_in[2];
    const float* sb   = (const float*)d_in[3];
    float* out = (float*)d_out;

    float* corrT      = (float*)d_ws;
    float* nrm_parts  = corrT + 4194304;
    float* tpar       = nrm_parts;            // alias: nrm_parts dead after nrm_reduce
    float* nrm_sq     = nrm_parts + 65536;
    float* smax       = nrm_sq + 8192;
    float* spar       = smax + 4096;
    float* tmax       = spar + 65536;
    float* pnorm      = tmax + 4096;
    float* ctxbuf     = pnorm + 8192;
    float* chunkbuf   = ctxbuf + 229376;

    pnorm_kernel<<<dim3(8, 16), 64, 0, stream>>>(src, tgt, pnorm);
    ctx_kernel<<<dim3(8, 32), 896, 0, stream>>>(src, tgt, pnorm, ctxbuf);

    // chunk 0
    conv_chunk<true><<<dim3(8, 8, 8), 256, 0, stream>>>(src, tgt, ctxbuf, sw, sb,
                                                        chunkbuf, nrm_parts, 0);
    corr_chunk<0><<<dim3(8, 16, 4), 256, 0, stream>>>(chunkbuf, nrm_sq, corrT, spar, tpar);
    // chunks 1,2
    for (int c = 1; c < 3; ++c) {
        conv_chunk<false><<<dim3(8, 8, 8), 256, 0, stream>>>(src, tgt, ctxbuf, sw, sb,
                                                             chunkbuf, nrm_parts, c * CCHNK);
        corr_chunk<1><<<dim3(8, 16, 4), 256, 0, stream>>>(chunkbuf, nrm_sq, corrT, spar, tpar);
    }
    // chunk 3: conv, then finalize norms, then corr with fused normalize+maxes
    conv_chunk<false><<<dim3(8, 8, 8), 256, 0, stream>>>(src, tgt, ctxbuf, sw, sb,
                                                         chunkbuf, nrm_parts, 3 * CCHNK);
    nrm_reduce<<<dim3(4, 8), 256, 0, stream>>>(nrm_parts, nrm_sq);
    corr_chunk<2><<<dim3(8, 16, 4), 256, 0, stream>>>(chunkbuf, nrm_sq, corrT, spar, tpar);

    combine_max<<<dim3(4, 4), 256, 0, stream>>>(spar, tpar, smax, tmax);
    final_kernel<<<dim3(64, 64, 4), 256, 0, stream>>>(corrT, smax, tmax, out);
}